// Round 3
// baseline (604.046 us; speedup 1.0000x reference)
//
#include <hip/hip_runtime.h>

typedef short short8 __attribute__((ext_vector_type(8)));
typedef short short4v __attribute__((ext_vector_type(4)));
typedef float f32x4 __attribute__((ext_vector_type(4)));
typedef unsigned short ushort_t;

#define DEV_INLINE __device__ __forceinline__

constexpr int NSEQ = 512, NRES = 384, CM = 256, CO = 32, CZ = 128;
constexpr float F_LN_EPS = 1e-5f, F_NORM_EPS = 1e-3f;

// workspace layout (bytes)
// Lt2: fragment-linear A: Lt2[(r>>4)*64 + (a>>3)][ (r&15)*8 + (a&7) ]
//      i.e. ((rowblk*64 + c32)*128 + ln*8 + e): 16-lane group reads 256B
//      contiguous per (rowblk, c32); q=0..3 consecutive c32 -> 1KB/wave.
constexpr size_t WS_LT   = 0;                                  // [768*64][128] bf16
constexpr size_t WS_RT   = WS_LT + (size_t)12288 * 512 * 2;    // [12288][512] bf16 row-major
constexpr size_t WS_WT   = WS_RT + (size_t)12288 * 512 * 2;    // [128 kc][128 f][8] bf16 (chunk-major)
constexpr size_t WS_NORM = WS_WT + (size_t)128 * 1024 * 2;     // [384][384] f32
constexpr size_t WS_PW   = WS_NORM + (size_t)384 * 384 * 4;    // [64][256] bf16 packed proj weights

DEV_INLINE ushort_t f2bf(float x) {
  union { float f; unsigned u; } v; v.f = x;
  unsigned r = v.u + 0x7FFFu + ((v.u >> 16) & 1u);
  return (ushort_t)(r >> 16);
}

DEV_INLINE short8 pack8(float4 a, float4 b) {
  short8 p;
  p[0] = (short)f2bf(a.x); p[1] = (short)f2bf(a.y);
  p[2] = (short)f2bf(a.z); p[3] = (short)f2bf(a.w);
  p[4] = (short)f2bf(b.x); p[5] = (short)f2bf(b.y);
  p[6] = (short)f2bf(b.z); p[7] = (short)f2bf(b.w);
  return p;
}

// async global->LDS, 16B per lane; lds dest = wave-uniform base + lane*16
DEV_INLINE void async16(const void* g, void* l) {
  __builtin_amdgcn_global_load_lds(
      (const __attribute__((address_space(1))) unsigned*)g,
      (__attribute__((address_space(3))) unsigned*)l, 16, 0, 0);
}

// ---------------------------------------------------------------------------
// Kernel: repack output_w [c][e][f] f32 -> WT2 chunk-major bf16:
// WT2[((k>>3)*128 + f)*8 + (k&7)] = W[k][f], k = c*32+e.
__global__ __launch_bounds__(256) void k_wt(const float* __restrict__ W,
                                            ushort_t* __restrict__ WT2) {
  int tid = blockIdx.x * 256 + threadIdx.x;      // 0..131071
  int k = tid >> 7, f = tid & 127;               // k = ce index 0..1023
  WT2[((size_t)(k >> 3) * 128 + f) * 8 + (k & 7)] = f2bf(W[(size_t)k * CZ + f]);
}

// ---------------------------------------------------------------------------
// Kernel: pack combined projection weights -> PW[64][256] bf16 (frag-linear).
__global__ __launch_bounds__(256) void k_pack(const float* __restrict__ left_w,
                                              const float* __restrict__ right_w,
                                              ushort_t* __restrict__ PW) {
  int id = blockIdx.x * 256 + threadIdx.x;   // 0..2047
  int o = id >> 5, ch = id & 31;             // 64 rows x 32 chunks of 8
  const float* src = (o < 32 ? left_w + (size_t)o * CM
                             : right_w + (size_t)(o - 32) * CM) + ch * 8;
  float4 a = *(const float4*)src, b = *(const float4*)(src + 4);
  *(short8*)&PW[(size_t)o * CM + ch * 8] = pack8(a, b);
}

// ---------------------------------------------------------------------------
// Kernel: norm[b][d] = sum_a mask[a][b]*mask[a][d]
__global__ __launch_bounds__(256) void k_norm(const float* __restrict__ mask,
                                              float* __restrict__ normM) {
  int b = blockIdx.x * 16 + threadIdx.x;
  int d = blockIdx.y * 16 + threadIdx.y;
  float a0 = 0.f, a1 = 0.f, a2 = 0.f, a3 = 0.f;
  for (int a = 0; a < NSEQ; a += 4) {
    a0 += mask[(size_t)(a + 0) * NRES + b] * mask[(size_t)(a + 0) * NRES + d];
    a1 += mask[(size_t)(a + 1) * NRES + b] * mask[(size_t)(a + 1) * NRES + d];
    a2 += mask[(size_t)(a + 2) * NRES + b] * mask[(size_t)(a + 2) * NRES + d];
    a3 += mask[(size_t)(a + 3) * NRES + b] * mask[(size_t)(a + 3) * NRES + d];
  }
  normM[(size_t)b * NRES + d] = (a0 + a1) + (a2 + a3);
}

// ---------------------------------------------------------------------------
// Kernel: LayerNorm + left/right projection. Left output now fragment-linear.
__global__ __launch_bounds__(256) void k_lnproj(
    const float* __restrict__ act, const float* __restrict__ mask,
    const float* __restrict__ ln_w, const float* __restrict__ ln_b,
    const float* __restrict__ left_b, const float* __restrict__ right_b,
    const ushort_t* __restrict__ PW,
    ushort_t* __restrict__ Lt2, ushort_t* __restrict__ Rt) {
  __shared__ ushort_t sAct[16 * 256];  // 8 KB: [row a][k], XOR-swizzled 16B chunks

  const int t = threadIdx.x;
  const int a0 = blockIdx.x * 16;
  const int b = blockIdx.y;
  const int r = t >> 4, c = t & 15;  // 16 lanes per row, 16 channels each

  const float4* arow =
      (const float4*)(act + ((size_t)(a0 + r) * NRES + b) * CM + c * 16);
  float4 v[4];
  float s = 0.f, ss = 0.f;
#pragma unroll
  for (int j = 0; j < 4; j++) {
    v[j] = arow[j];
    s += v[j].x + v[j].y + v[j].z + v[j].w;
    ss += v[j].x * v[j].x + v[j].y * v[j].y + v[j].z * v[j].z + v[j].w * v[j].w;
  }
  s += __shfl_xor(s, 1);  s += __shfl_xor(s, 2);
  s += __shfl_xor(s, 4);  s += __shfl_xor(s, 8);
  ss += __shfl_xor(ss, 1); ss += __shfl_xor(ss, 2);
  ss += __shfl_xor(ss, 4); ss += __shfl_xor(ss, 8);
  const float mu = s * (1.f / CM);
  const float rs = rsqrtf(ss * (1.f / CM) - mu * mu + F_LN_EPS);

  const int lane = t & 63, w = t >> 6;
  const int q = lane >> 4, ln = lane & 15;
  short8 bfrag[8];
#pragma unroll
  for (int ks = 0; ks < 8; ks++)
    bfrag[ks] = *(const short8*)&PW[(size_t)(w * 16 + ln) * CM + (ks * 4 + q) * 8];

#pragma unroll
  for (int j = 0; j < 2; j++) {
    int cb = c * 16 + j * 8;
    float4 lw0 = *(const float4*)(ln_w + cb), lw1 = *(const float4*)(ln_w + cb + 4);
    float4 lb0 = *(const float4*)(ln_b + cb), lb1 = *(const float4*)(ln_b + cb + 4);
    float4 x0 = v[2 * j], x1 = v[2 * j + 1], y0, y1;
    y0.x = (x0.x - mu) * rs * lw0.x + lb0.x;
    y0.y = (x0.y - mu) * rs * lw0.y + lb0.y;
    y0.z = (x0.z - mu) * rs * lw0.z + lb0.z;
    y0.w = (x0.w - mu) * rs * lw0.w + lb0.w;
    y1.x = (x1.x - mu) * rs * lw1.x + lb1.x;
    y1.y = (x1.y - mu) * rs * lw1.y + lb1.y;
    y1.z = (x1.z - mu) * rs * lw1.z + lb1.z;
    y1.w = (x1.w - mu) * rs * lw1.w + lb1.w;
    int chunk = c * 2 + j;
    *(short8*)&sAct[r * 256 + ((chunk ^ (r & 7)) * 8)] = pack8(y0, y1);
  }
  __syncthreads();

  f32x4 acc = {0, 0, 0, 0};
#pragma unroll
  for (int ks = 0; ks < 8; ks++) {
    int kc = ks * 4 + q;
    short8 af = *(const short8*)&sAct[ln * 256 + ((kc ^ (ln & 7)) * 8)];
    acc = __builtin_amdgcn_mfma_f32_16x16x32_bf16(af, bfrag[ks], acc, 0, 0, 0);
  }

  const int o = w * 16 + ln;
  float mk[4];
#pragma unroll
  for (int reg = 0; reg < 4; reg++)
    mk[reg] = mask[(size_t)(a0 + q * 4 + reg) * NRES + b];
  float bias = (o < 32) ? left_b[o] : right_b[o - 32];
  short4v pk;
#pragma unroll
  for (int reg = 0; reg < 4; reg++)
    pk[reg] = (short)f2bf((acc[reg] + bias) * mk[reg]);

  const int a = a0 + q * 4;  // 4 consecutive a (k-index), (a&7) in {0,4}
  if (o < 32) {
    int rr = b * 32 + o;     // M row
    *(short4v*)&Lt2[((size_t)(rr >> 4) * 64 + (a >> 3)) * 128 + (rr & 15) * 8 + (a & 7)] = pk;
  } else {
    *(short4v*)&Rt[(size_t)(b * 32 + (o - 32)) * NSEQ + a] = pk;
  }
}

// ---------------------------------------------------------------------------
// Fused double-GEMM: per block = 4x4 residue pairs.
// GEMM1: P[128 (b,c)][128 (d,e)] = sum_a Lt * Rt (K=512)
//   A fragments DIRECT from global (fragment-linear Lt2, 1KB coalesced per
//   wave, L2-hot: consecutive blocks share the A panel since m0=blockIdx.y).
//   B staged in LDS (16KB x2 dbuf, pre-swizzled source + swizzled ds_read),
//   2-phase pipeline: issue B-stage + A-regs for kt+1, compute kt,
//   vmcnt(0)+barrier. LDS traffic halved vs both-operand staging.
// GEMM2: out[16 pair][128 f] = P2[16][1024] x W; W direct from global.
__global__ __launch_bounds__(256, 2) void k_opm(
    const ushort_t* __restrict__ Lt2, const ushort_t* __restrict__ Rt,
    const ushort_t* __restrict__ WT2, const float* __restrict__ normM,
    const float* __restrict__ out_b, float* __restrict__ out) {
  __shared__ ushort_t smem[16384];   // 32 KB: 2 x (B 16KB); sP overlays all
  ushort_t* sP = smem;               // 32 KB: P2 [16][1024]

  const int t = threadIdx.x, lane = t & 63, w = t >> 6;
  const int q = lane >> 4, ln = lane & 15;
  const int wm = w & 1, wn = w >> 1;           // 2x2 wave grid
  const int mby = blockIdx.y, nbx = blockIdx.x;  // m on SLOW axis: A-panel reuse
  const int m0 = mby * 128, n0 = nbx * 128;
  const int srow8 = lane >> 3, schunk = lane & 7;  // staging lane map

  // stage one BK=64 B-tile (16KB) into buffer c. 4 async16/thread.
  auto STAGE_B = [&](int kt, int c) {
    char* base = (char*)smem + c * 16384;
#pragma unroll
    for (int i = 0; i < 4; i++) {
      int rg = w + i * 4;            // 1KB region 0..15
      int r = rg * 8 + srow8;        // tile row 0..127
      int gc = schunk ^ (r & 7);     // swizzle on global side
      async16(Rt + (size_t)(n0 + r) * NSEQ + kt * 64 + gc * 8, base + rg * 1024);
    }
  };

  // load this thread's A fragments for one K-tile straight from global.
  // lane (q,ln): row m0+wm*64+tm*16+ln, k-chunk c32 = kt*8+ks*4+q.
  auto LOAD_A = [&](int kt, short8 dst[2][4]) {
#pragma unroll
    for (int ks = 0; ks < 2; ks++) {
      int c32 = kt * 8 + ks * 4 + q;
#pragma unroll
      for (int tm = 0; tm < 4; tm++) {
        size_t idx = ((size_t)(mby * 8 + wm * 4 + tm) * 64 + c32) * 128 + ln * 8;
        dst[ks][tm] = *(const short8*)&Lt2[idx];
      }
    }
  };

  f32x4 acc1[4][4];
#pragma unroll
  for (int i = 0; i < 4; i++)
#pragma unroll
    for (int j = 0; j < 4; j++) acc1[i][j] = {0, 0, 0, 0};

  short8 afb[2][2][4];  // [kt&1][ks][tm] register ping-pong

  // ================= GEMM1: K=512, BK=64, 8 tiles, 2-phase pipeline =========
  STAGE_B(0, 0);
  LOAD_A(0, afb[0]);
  asm volatile("s_waitcnt vmcnt(0)" ::: "memory");
  __builtin_amdgcn_s_barrier();
#pragma unroll
  for (int kt = 0; kt < 8; kt++) {
    const int cur = kt & 1;
    if (kt + 1 < 8) {
      STAGE_B(kt + 1, cur ^ 1);      // B loads for kt+1 in flight
      LOAD_A(kt + 1, afb[cur ^ 1]);  // A regs for kt+1 in flight
    }
    const ushort_t* bB = smem + cur * 8192;
#pragma unroll
    for (int ks = 0; ks < 2; ks++) {
      int kc = ks * 4 + q;  // chunk within row, 0..7
      short8 bf[4];
#pragma unroll
      for (int tn = 0; tn < 4; tn++) {
        int rr = wn * 64 + tn * 16 + ln;
        bf[tn] = *(const short8*)&bB[rr * 64 + ((kc ^ (rr & 7)) * 8)];
      }
      __builtin_amdgcn_s_setprio(1);
#pragma unroll
      for (int tm = 0; tm < 4; tm++)
#pragma unroll
        for (int tn = 0; tn < 4; tn++)
          acc1[tm][tn] = __builtin_amdgcn_mfma_f32_16x16x32_bf16(
              afb[cur][ks][tm], bf[tn], acc1[tm][tn], 0, 0, 0);
      __builtin_amdgcn_s_setprio(0);
    }
    // drain: kt+1 B-stage + A-regs complete; all waves done reading cur buf
    asm volatile("s_waitcnt vmcnt(0)" ::: "memory");
    __builtin_amdgcn_s_barrier();
  }

  // ============ P -> LDS bf16, layout [pair][ce] swizzled ============
  __syncthreads();
#pragma unroll
  for (int tm = 0; tm < 4; tm++) {
#pragma unroll
    for (int tn = 0; tn < 4; tn++) {
      int pair = (wm * 2 + (tm >> 1)) * 4 + (wn * 2 + (tn >> 1));
      int e = (tn & 1) * 16 + ln;
#pragma unroll
      for (int reg = 0; reg < 4; reg++) {
        int c = (tm & 1) * 16 + q * 4 + reg;
        int ce = c * 32 + e;
        int pos = (ce >> 3) ^ (pair & 7);
        sP[pair * 1024 + pos * 8 + (ce & 7)] = f2bf(acc1[tm][tn][reg]);
      }
    }
  }
  __syncthreads();

  // ================= GEMM2: K=1024, W direct from global, no barriers =======
  f32x4 acc2[2] = {{0, 0, 0, 0}, {0, 0, 0, 0}};
#pragma unroll
  for (int kt = 0; kt < 16; kt++) {
#pragma unroll
    for (int ks = 0; ks < 2; ks++) {
      int c16 = kt * 8 + ks * 4 + q;  // 16B k-chunk 0..127
      short8 af = *(const short8*)&sP[ln * 1024 + ((c16 ^ (ln & 7)) * 8)];
#pragma unroll
      for (int tn = 0; tn < 2; tn++) {
        int fr = w * 32 + tn * 16 + ln;
        short8 bfr = *(const short8*)&WT2[((size_t)c16 * 128 + fr) * 8];
        acc2[tn] = __builtin_amdgcn_mfma_f32_16x16x32_bf16(af, bfr, acc2[tn], 0, 0, 0);
      }
    }
  }

  // ================= epilogue =================
  const int b = mby * 4 + q;  // pair = q*4+reg -> bb=q (M side), dd=reg (N side)
#pragma unroll
  for (int reg = 0; reg < 4; reg++) {
    int d = nbx * 4 + reg;
    float inv = 1.f / (F_NORM_EPS + normM[(size_t)b * NRES + d]);
#pragma unroll
    for (int tn = 0; tn < 2; tn++) {
      int f = w * 32 + tn * 16 + ln;
      out[((size_t)b * NRES + d) * CZ + f] = (acc2[tn][reg] + out_b[f]) * inv;
    }
  }
}

// ---------------------------------------------------------------------------
extern "C" void kernel_launch(void* const* d_in, const int* in_sizes, int n_in,
                              void* d_out, int out_size, void* d_ws, size_t ws_size,
                              hipStream_t stream) {
  (void)in_sizes; (void)n_in; (void)out_size; (void)ws_size;
  const float* act      = (const float*)d_in[0];
  const float* mask     = (const float*)d_in[1];
  const float* ln_w     = (const float*)d_in[2];
  const float* ln_b     = (const float*)d_in[3];
  const float* left_w   = (const float*)d_in[4];
  const float* left_b   = (const float*)d_in[5];
  const float* right_w  = (const float*)d_in[6];
  const float* right_b  = (const float*)d_in[7];
  const float* output_w = (const float*)d_in[8];
  const float* output_b = (const float*)d_in[9];
  float* out = (float*)d_out;

  char* ws = (char*)d_ws;
  ushort_t* Lt2 = (ushort_t*)(ws + WS_LT);
  ushort_t* Rt  = (ushort_t*)(ws + WS_RT);
  ushort_t* WT2 = (ushort_t*)(ws + WS_WT);
  float* normM  = (float*)(ws + WS_NORM);
  ushort_t* PW  = (ushort_t*)(ws + WS_PW);

  hipLaunchKernelGGL(k_pack, dim3(8), dim3(256), 0, stream, left_w, right_w, PW);
  hipLaunchKernelGGL(k_wt, dim3(512), dim3(256), 0, stream, output_w, WT2);
  hipLaunchKernelGGL(k_norm, dim3(24, 24), dim3(16, 16), 0, stream, mask, normM);
  hipLaunchKernelGGL(k_lnproj, dim3(32, 384), dim3(256), 0, stream, act, mask,
                     ln_w, ln_b, left_b, right_b, PW, Lt2, Rt);
  hipLaunchKernelGGL(k_opm, dim3(96, 96), dim3(256), 0, stream, Lt2, Rt, WT2,
                     normM, output_b, out);
}

// Round 4
// 559.225 us; speedup vs baseline: 1.0801x; 1.0801x over previous
//
#include <hip/hip_runtime.h>

typedef short short8 __attribute__((ext_vector_type(8)));
typedef short short4v __attribute__((ext_vector_type(4)));
typedef float f32x4 __attribute__((ext_vector_type(4)));
typedef unsigned short ushort_t;

#define DEV_INLINE __device__ __forceinline__

constexpr int NSEQ = 512, NRES = 384, CM = 256, CO = 32, CZ = 128;
constexpr float F_LN_EPS = 1e-5f, F_NORM_EPS = 1e-3f;

// workspace layout (bytes)
constexpr size_t WS_LT   = 0;                                  // [12288][512] bf16 row-major
constexpr size_t WS_RT   = WS_LT + (size_t)12288 * 512 * 2;    // [12288][512] bf16 row-major
constexpr size_t WS_WT   = WS_RT + (size_t)12288 * 512 * 2;    // [128 kc][128 f][8] bf16 chunk-major
constexpr size_t WS_NORM = WS_WT + (size_t)128 * 1024 * 2;     // [384][384] f32
constexpr size_t WS_PW   = WS_NORM + (size_t)384 * 384 * 4;    // [64][256] bf16 packed proj weights

DEV_INLINE ushort_t f2bf(float x) {
  union { float f; unsigned u; } v; v.f = x;
  unsigned r = v.u + 0x7FFFu + ((v.u >> 16) & 1u);
  return (ushort_t)(r >> 16);
}

DEV_INLINE short8 pack8(float4 a, float4 b) {
  short8 p;
  p[0] = (short)f2bf(a.x); p[1] = (short)f2bf(a.y);
  p[2] = (short)f2bf(a.z); p[3] = (short)f2bf(a.w);
  p[4] = (short)f2bf(b.x); p[5] = (short)f2bf(b.y);
  p[6] = (short)f2bf(b.z); p[7] = (short)f2bf(b.w);
  return p;
}

// async global->LDS, 16B per lane; lds dest = wave-uniform base + lane*16
DEV_INLINE void async16(const void* g, void* l) {
  __builtin_amdgcn_global_load_lds(
      (const __attribute__((address_space(1))) unsigned*)g,
      (__attribute__((address_space(3))) unsigned*)l, 16, 0, 0);
}

// ---------------------------------------------------------------------------
// Kernel: repack output_w [c][e][f] f32 -> WT2 chunk-major bf16:
// WT2[(kc*128 + f)*8 + e] = W[(kc*8+e)][f].  Coalesced 16B writes.
__global__ __launch_bounds__(256) void k_wt(const float* __restrict__ W,
                                            ushort_t* __restrict__ WT2) {
  int tid = blockIdx.x * 256 + threadIdx.x;      // 0..16383
  int kc = tid >> 7, f = tid & 127;              // kc 0..127
  short8 p;
#pragma unroll
  for (int e = 0; e < 8; e++)
    p[e] = (short)f2bf(W[(size_t)(kc * 8 + e) * CZ + f]);
  *(short8*)&WT2[((size_t)kc * 128 + f) * 8] = p;
}

// ---------------------------------------------------------------------------
// Kernel: pack combined projection weights -> PW[64][256] bf16 (frag-linear).
__global__ __launch_bounds__(256) void k_pack(const float* __restrict__ left_w,
                                              const float* __restrict__ right_w,
                                              ushort_t* __restrict__ PW) {
  int id = blockIdx.x * 256 + threadIdx.x;   // 0..2047
  int o = id >> 5, ch = id & 31;             // 64 rows x 32 chunks of 8
  const float* src = (o < 32 ? left_w + (size_t)o * CM
                             : right_w + (size_t)(o - 32) * CM) + ch * 8;
  float4 a = *(const float4*)src, b = *(const float4*)(src + 4);
  *(short8*)&PW[(size_t)o * CM + ch * 8] = pack8(a, b);
}

// ---------------------------------------------------------------------------
// Kernel: norm[b][d] = sum_a mask[a][b]*mask[a][d]
__global__ __launch_bounds__(256) void k_norm(const float* __restrict__ mask,
                                              float* __restrict__ normM) {
  int b = blockIdx.x * 16 + threadIdx.x;
  int d = blockIdx.y * 16 + threadIdx.y;
  float a0 = 0.f, a1 = 0.f, a2 = 0.f, a3 = 0.f;
  for (int a = 0; a < NSEQ; a += 4) {
    a0 += mask[(size_t)(a + 0) * NRES + b] * mask[(size_t)(a + 0) * NRES + d];
    a1 += mask[(size_t)(a + 1) * NRES + b] * mask[(size_t)(a + 1) * NRES + d];
    a2 += mask[(size_t)(a + 2) * NRES + b] * mask[(size_t)(a + 2) * NRES + d];
    a3 += mask[(size_t)(a + 3) * NRES + b] * mask[(size_t)(a + 3) * NRES + d];
  }
  normM[(size_t)b * NRES + d] = (a0 + a1) + (a2 + a3);
}

// ---------------------------------------------------------------------------
// Kernel: LayerNorm + left/right projection (round-2 version: row-major out).
__global__ __launch_bounds__(256) void k_lnproj(
    const float* __restrict__ act, const float* __restrict__ mask,
    const float* __restrict__ ln_w, const float* __restrict__ ln_b,
    const float* __restrict__ left_b, const float* __restrict__ right_b,
    const ushort_t* __restrict__ PW,
    ushort_t* __restrict__ Lt, ushort_t* __restrict__ Rt) {
  __shared__ ushort_t sAct[16 * 256];  // 8 KB: [row a][k], XOR-swizzled 16B chunks

  const int t = threadIdx.x;
  const int a0 = blockIdx.x * 16;
  const int b = blockIdx.y;
  const int r = t >> 4, c = t & 15;  // 16 lanes per row, 16 channels each

  const float4* arow =
      (const float4*)(act + ((size_t)(a0 + r) * NRES + b) * CM + c * 16);
  float4 v[4];
  float s = 0.f, ss = 0.f;
#pragma unroll
  for (int j = 0; j < 4; j++) {
    v[j] = arow[j];
    s += v[j].x + v[j].y + v[j].z + v[j].w;
    ss += v[j].x * v[j].x + v[j].y * v[j].y + v[j].z * v[j].z + v[j].w * v[j].w;
  }
  s += __shfl_xor(s, 1);  s += __shfl_xor(s, 2);
  s += __shfl_xor(s, 4);  s += __shfl_xor(s, 8);
  ss += __shfl_xor(ss, 1); ss += __shfl_xor(ss, 2);
  ss += __shfl_xor(ss, 4); ss += __shfl_xor(ss, 8);
  const float mu = s * (1.f / CM);
  const float rs = rsqrtf(ss * (1.f / CM) - mu * mu + F_LN_EPS);

  const int lane = t & 63, w = t >> 6;
  const int q = lane >> 4, ln = lane & 15;
  short8 bfrag[8];
#pragma unroll
  for (int ks = 0; ks < 8; ks++)
    bfrag[ks] = *(const short8*)&PW[(size_t)(w * 16 + ln) * CM + (ks * 4 + q) * 8];

#pragma unroll
  for (int j = 0; j < 2; j++) {
    int cb = c * 16 + j * 8;
    float4 lw0 = *(const float4*)(ln_w + cb), lw1 = *(const float4*)(ln_w + cb + 4);
    float4 lb0 = *(const float4*)(ln_b + cb), lb1 = *(const float4*)(ln_b + cb + 4);
    float4 x0 = v[2 * j], x1 = v[2 * j + 1], y0, y1;
    y0.x = (x0.x - mu) * rs * lw0.x + lb0.x;
    y0.y = (x0.y - mu) * rs * lw0.y + lb0.y;
    y0.z = (x0.z - mu) * rs * lw0.z + lb0.z;
    y0.w = (x0.w - mu) * rs * lw0.w + lb0.w;
    y1.x = (x1.x - mu) * rs * lw1.x + lb1.x;
    y1.y = (x1.y - mu) * rs * lw1.y + lb1.y;
    y1.z = (x1.z - mu) * rs * lw1.z + lb1.z;
    y1.w = (x1.w - mu) * rs * lw1.w + lb1.w;
    int chunk = c * 2 + j;
    *(short8*)&sAct[r * 256 + ((chunk ^ (r & 7)) * 8)] = pack8(y0, y1);
  }
  __syncthreads();

  f32x4 acc = {0, 0, 0, 0};
#pragma unroll
  for (int ks = 0; ks < 8; ks++) {
    int kc = ks * 4 + q;
    short8 af = *(const short8*)&sAct[ln * 256 + ((kc ^ (ln & 7)) * 8)];
    acc = __builtin_amdgcn_mfma_f32_16x16x32_bf16(af, bfrag[ks], acc, 0, 0, 0);
  }

  const int o = w * 16 + ln;
  float mk[4];
#pragma unroll
  for (int reg = 0; reg < 4; reg++)
    mk[reg] = mask[(size_t)(a0 + q * 4 + reg) * NRES + b];
  float bias = (o < 32) ? left_b[o] : right_b[o - 32];
  ushort_t* dst = (o < 32) ? (Lt + (size_t)(b * 32 + o) * NSEQ)
                           : (Rt + (size_t)(b * 32 + (o - 32)) * NSEQ);
  short4v pk;
#pragma unroll
  for (int reg = 0; reg < 4; reg++)
    pk[reg] = (short)f2bf((acc[reg] + bias) * mk[reg]);
  *(short4v*)&dst[a0 + q * 4] = pk;
}

// ---------------------------------------------------------------------------
// Fused double-GEMM, 256x256 tiles (8 waves, 512 threads, 2x4 wave grid).
// GEMM1: P[256 (b,c)][256 (d,e)] = sum_a Lt * Rt, K=512, BK=64,
//   2-phase pipeline (round-2 proven): stage kt+1, compute kt, vmcnt(0)+bar.
//   Pre-swizzled global source + swizzled ds_read (both-sides rule).
// GEMM2: 64 pairs x 128 f, K=1024. Each wave owns a DISJOINT 16-wide f-slice
//   -> W read once per block (256KB, no duplication), direct from L2-resident
//   WT2, no staging, no barriers. sP = 64x1024 bf16 = 128KB overlays dbuf.
// Rationale: L2 traffic/block was the wall (4.7GB total at 128^2 tiles);
// 256^2 cuts it to ~1.8GB (52us floor) vs 77us MFMA floor.
__global__ __launch_bounds__(512, 2) void k_opm(
    const ushort_t* __restrict__ Lt, const ushort_t* __restrict__ Rt,
    const ushort_t* __restrict__ WT2, const float* __restrict__ normM,
    const float* __restrict__ out_b, float* __restrict__ out) {
  __shared__ ushort_t smem[65536];   // 128 KB: 2 x (A 32KB + B 32KB); sP overlays
  ushort_t* sP = smem;               // 128 KB: P2 [64 pair][1024 ce] swizzled

  const int t = threadIdx.x, lane = t & 63, w = t >> 6;   // w 0..7
  const int q = lane >> 4, ln = lane & 15;
  const int wm = w >> 2, wn = w & 3;                      // 2x4 wave grid
  const int m0 = blockIdx.x * 256, n0 = blockIdx.y * 256;

  // stage one BK=64 tile (A 32KB + B 32KB) into buffer c. 8 async16/thread.
  // LDS dest linear [r][64k]; global source pre-swizzled.
  auto STAGE = [&](int kt, int c) {
    ushort_t* base = smem + c * 32768;
#pragma unroll
    for (int j = 0; j < 4; j++) {
      int r = j * 64 + (t >> 3);       // tile row 0..255
      int gc = (t & 7) ^ (r & 7);      // swizzle on global side
      async16(Lt + (size_t)(m0 + r) * NSEQ + kt * 64 + gc * 8,
              base + j * 4096 + t * 8);
      async16(Rt + (size_t)(n0 + r) * NSEQ + kt * 64 + gc * 8,
              base + 16384 + j * 4096 + t * 8);
    }
  };

  f32x4 acc1[8][4];
#pragma unroll
  for (int i = 0; i < 8; i++)
#pragma unroll
    for (int j = 0; j < 4; j++) acc1[i][j] = {0, 0, 0, 0};

  // ================= GEMM1: K=512, BK=64, 8 tiles, 2-phase pipeline =========
  STAGE(0, 0);
  asm volatile("s_waitcnt vmcnt(0)" ::: "memory");
  __builtin_amdgcn_s_barrier();
#pragma unroll
  for (int kt = 0; kt < 8; kt++) {
    const int cur = kt & 1;
    if (kt + 1 < 8) STAGE(kt + 1, cur ^ 1);  // next-tile loads in flight

    const ushort_t* bA = smem + cur * 32768;
    const ushort_t* bB = bA + 16384;
#pragma unroll
    for (int ks = 0; ks < 2; ks++) {
      int kc = ks * 4 + q;  // chunk within row, 0..7
      short8 af[8], bf[4];
#pragma unroll
      for (int tm = 0; tm < 8; tm++) {
        int rr = wm * 128 + tm * 16 + ln;
        af[tm] = *(const short8*)&bA[rr * 64 + ((kc ^ (rr & 7)) * 8)];
      }
#pragma unroll
      for (int tn = 0; tn < 4; tn++) {
        int rr = wn * 64 + tn * 16 + ln;
        bf[tn] = *(const short8*)&bB[rr * 64 + ((kc ^ (rr & 7)) * 8)];
      }
      __builtin_amdgcn_s_setprio(1);
#pragma unroll
      for (int tm = 0; tm < 8; tm++)
#pragma unroll
        for (int tn = 0; tn < 4; tn++)
          acc1[tm][tn] = __builtin_amdgcn_mfma_f32_16x16x32_bf16(
              af[tm], bf[tn], acc1[tm][tn], 0, 0, 0);
      __builtin_amdgcn_s_setprio(0);
    }
    // next tile staged + all waves done reading cur before it's overwritten
    asm volatile("s_waitcnt vmcnt(0)" ::: "memory");
    __builtin_amdgcn_s_barrier();
  }

  // ============ P -> LDS bf16, layout [pair 0..63][ce] swizzled ============
  __syncthreads();
#pragma unroll
  for (int tm = 0; tm < 8; tm++) {
#pragma unroll
    for (int tn = 0; tn < 4; tn++) {
#pragma unroll
      for (int reg = 0; reg < 4; reg++) {
        int mabs = wm * 128 + tm * 16 + q * 4 + reg;  // row in 256-tile
        int nabs = wn * 64 + tn * 16 + ln;            // col in 256-tile
        int pair = (mabs >> 5) * 8 + (nabs >> 5);     // 0..63
        int ce = (mabs & 31) * 32 + (nabs & 31);      // 0..1023
        int pos = (ce >> 3) ^ (pair & 7);
        sP[pair * 1024 + pos * 8 + (ce & 7)] = f2bf(acc1[tm][tn][reg]);
      }
    }
  }
  __syncthreads();

  // ====== GEMM2: K=1024, M=64 pairs, wave w owns f-slice w*16..w*16+15 ======
  f32x4 acc2[4] = {{0, 0, 0, 0}, {0, 0, 0, 0}, {0, 0, 0, 0}, {0, 0, 0, 0}};
#pragma unroll
  for (int kt = 0; kt < 16; kt++) {
#pragma unroll
    for (int ks = 0; ks < 2; ks++) {
      int c16 = kt * 8 + ks * 4 + q;  // 16B k-chunk 0..127
      short8 bfr = *(const short8*)&WT2[((size_t)c16 * 128 + w * 16 + ln) * 8];
#pragma unroll
      for (int tm2 = 0; tm2 < 4; tm2++) {
        int p = tm2 * 16 + ln;        // pair row 0..63
        short8 af = *(const short8*)&sP[p * 1024 + ((c16 ^ (p & 7)) * 8)];
        acc2[tm2] = __builtin_amdgcn_mfma_f32_16x16x32_bf16(af, bfr, acc2[tm2], 0, 0, 0);
      }
    }
  }

  // ================= epilogue =================
  const int f = w * 16 + ln;
  const float ob = out_b[f];
#pragma unroll
  for (int tm2 = 0; tm2 < 4; tm2++) {
#pragma unroll
    for (int reg = 0; reg < 4; reg++) {
      int p = tm2 * 16 + q * 4 + reg;               // pair = C row
      int b = blockIdx.x * 8 + (p >> 3);
      int d = blockIdx.y * 8 + (p & 7);
      float inv = 1.f / (F_NORM_EPS + normM[(size_t)b * NRES + d]);
      out[((size_t)b * NRES + d) * CZ + f] = (acc2[tm2][reg] + ob) * inv;
    }
  }
}

// ---------------------------------------------------------------------------
extern "C" void kernel_launch(void* const* d_in, const int* in_sizes, int n_in,
                              void* d_out, int out_size, void* d_ws, size_t ws_size,
                              hipStream_t stream) {
  (void)in_sizes; (void)n_in; (void)out_size; (void)ws_size;
  const float* act      = (const float*)d_in[0];
  const float* mask     = (const float*)d_in[1];
  const float* ln_w     = (const float*)d_in[2];
  const float* ln_b     = (const float*)d_in[3];
  const float* left_w   = (const float*)d_in[4];
  const float* left_b   = (const float*)d_in[5];
  const float* right_w  = (const float*)d_in[6];
  const float* right_b  = (const float*)d_in[7];
  const float* output_w = (const float*)d_in[8];
  const float* output_b = (const float*)d_in[9];
  float* out = (float*)d_out;

  char* ws = (char*)d_ws;
  ushort_t* Lt  = (ushort_t*)(ws + WS_LT);
  ushort_t* Rt  = (ushort_t*)(ws + WS_RT);
  ushort_t* WT2 = (ushort_t*)(ws + WS_WT);
  float* normM  = (float*)(ws + WS_NORM);
  ushort_t* PW  = (ushort_t*)(ws + WS_PW);

  hipLaunchKernelGGL(k_pack, dim3(8), dim3(256), 0, stream, left_w, right_w, PW);
  hipLaunchKernelGGL(k_wt, dim3(64), dim3(256), 0, stream, output_w, WT2);
  hipLaunchKernelGGL(k_norm, dim3(24, 24), dim3(16, 16), 0, stream, mask, normM);
  hipLaunchKernelGGL(k_lnproj, dim3(32, 384), dim3(256), 0, stream, act, mask,
                     ln_w, ln_b, left_b, right_b, PW, Lt, Rt);
  hipLaunchKernelGGL(k_opm, dim3(48, 48), dim3(512), 0, stream, Lt, Rt, WT2,
                     normM, output_b, out);
}